// Round 5
// baseline (388.170 us; speedup 1.0000x reference)
//
#include <hip/hip_runtime.h>
#include <stdint.h>

// Problem constants
#define L_   3969         // patches
#define LP   3972         // padded L (mult of 4, for float4 loads)
#define EPS_ 1e-5f
#define LOG2E 1.4426950408889634f
#define MH   6            // split over im (patch-row chunks) in K3
#define IMR  11           // im rows per chunk (6*11 >= 63)

// workspace layout (float offsets). Total 6,720,608 floats = 26.9 MB
#define OFF_MF   0          // [2][64][LP] fg mean
#define OFF_SF   508416     // fg var
#define OFF_MB   1016832    // bg mean
#define OFF_SB   1525248    // bg var
#define OFF_TOKF 2033664    // [2 b][LP][64 c]  (l-major rows, 256B aligned)
#define OFF_TOKB 2542080
#define OFF_PACC 3050496    // [MH][2 b][LP][64]; slice p=0 doubles as NSTD after merge
#define OFF_PM   6100992    // [MH][2][LP]
#define OFF_PD   6148656
#define OFF_WT   6196320    // W2: bf16 frag-ordered weights [t][c][kci][dq][hl][lane][8] (1M bf16)

typedef __attribute__((ext_vector_type(8))) short bf16x8;   // 8 bf16 (4 VGPRs)
typedef __attribute__((ext_vector_type(4))) float f32x4;    // MFMA accumulator

__device__ __forceinline__ uint16_t bf16_rne(float f) {
    uint32_t u = __float_as_uint(f);
    return (uint16_t)((u + 0x7FFFu + ((u >> 16) & 1u)) >> 16);
}
// hi = truncated top-16 bits (exact), lo = RNE(residual): hi+lo ~ 2^-17 relative
__device__ __forceinline__ void split_bf16(float v, uint16_t& h, uint16_t& l) {
    uint32_t u = __float_as_uint(v);
    uint32_t hu = u & 0xFFFF0000u;
    h = (uint16_t)(hu >> 16);
    l = bf16_rne(v - __uint_as_float(hu));
}
__device__ __forceinline__ uint4 pack8(const uint16_t* s) {
    uint4 r;
    r.x = (uint32_t)s[0] | ((uint32_t)s[1] << 16);
    r.y = (uint32_t)s[2] | ((uint32_t)s[3] << 16);
    r.z = (uint32_t)s[4] | ((uint32_t)s[5] << 16);
    r.w = (uint32_t)s[6] | ((uint32_t)s[7] << 16);
    return r;
}

// ---------------- K0: weights -> split-bf16 MFMA A-fragment layout ----------------
__global__ void k0_w2(const float* __restrict__ wf, const float* __restrict__ wb,
                      float* __restrict__ ws) {
    int c = blockIdx.x, t = blockIdx.y;
    const float* w = t ? wb : wf;
    uint16_t* w2 = (uint16_t*)(ws + OFF_WT);
    int tid = threadIdx.x;
    int lane = tid & 63, dq = tid >> 6;
    int d = dq * 16 + (lane & 15), quad = lane >> 4;
    for (int kci = 0; kci < 2; ++kci) {
        int k = kci * 32 + quad * 8;
        const float* src = w + (size_t)(d * 64 + c) * 64 + k;
        uint16_t hb[8], lb[8];
#pragma unroll
        for (int j = 0; j < 8; ++j) split_bf16(src[j], hb[j], lb[j]);
        size_t base = ((size_t)(((t * 64 + c) * 2 + kci) * 4 + dq) * 2) * 512 + lane * 8;
        *(uint4*)(w2 + base) = pack8(hb);
        *(uint4*)(w2 + base + 512) = pack8(lb);
    }
}

// ---------------- K1: per-patch fg/bg stats ----------------
__global__ void k1_stats(const float* __restrict__ x, const float* __restrict__ mask,
                         float* __restrict__ ws) {
    int i = blockIdx.x, c = blockIdx.y, b = blockIdx.z;
    __shared__ float xs[8 * 256];
    __shared__ float ms[8 * 256];
    __shared__ float pS[5][256];
    int t = threadIdx.x;
    const float* xr = x + (((b * 64 + c) * 256) + i * 4) * 256;
    const float* mr = mask + (b * 256 + i * 4) * 256;
#pragma unroll
    for (int r = 0; r < 8; ++r) {
        xs[r * 256 + t] = xr[r * 256 + t];
        ms[r * 256 + t] = mr[r * 256 + t];
    }
    __syncthreads();
    int q = t >> 6, j = t & 63;
    float Sa = 0, Qa = 0, Sf = 0, Qf = 0, Nf = 0;
    if (j < 63) {
#pragma unroll
        for (int rr = 0; rr < 2; ++rr) {
            int base = (q * 2 + rr) * 256 + j * 4;
#pragma unroll
            for (int cc = 0; cc < 8; ++cc) {
                float v = xs[base + cc], m = ms[base + cc];
                Sa += v; Qa += v * v; Sf += v * m; Qf += v * v * m; Nf += m;
            }
        }
    }
    pS[0][t] = Sa; pS[1][t] = Qa; pS[2][t] = Sf; pS[3][t] = Qf; pS[4][t] = Nf;
    __syncthreads();
    if (q == 0 && j < 63) {
        Sa = pS[0][j] + pS[0][j + 64] + pS[0][j + 128] + pS[0][j + 192];
        Qa = pS[1][j] + pS[1][j + 64] + pS[1][j + 128] + pS[1][j + 192];
        Sf = pS[2][j] + pS[2][j + 64] + pS[2][j + 128] + pS[2][j + 192];
        Qf = pS[3][j] + pS[3][j + 64] + pS[3][j + 128] + pS[3][j + 192];
        Nf = pS[4][j] + pS[4][j + 64] + pS[4][j + 128] + pS[4][j + 192];
        float nb = 64.0f - Nf;
        float muf = Sf / (Nf + EPS_);
        float vaf = (Qf - 2.f * muf * Sf + Nf * muf * muf) / (Nf + EPS_);
        float Sb = Sa - Sf, Qb = Qa - Qf;
        float mub = Sb / (nb + EPS_);
        float vab = (Qb - 2.f * mub * Sb + nb * mub * mub) / (nb + EPS_);
        int idx = (b * 64 + c) * LP + i * 63 + j;
        ws[OFF_MF + idx] = muf; ws[OFF_SF + idx] = vaf;
        ws[OFF_MB + idx] = mub; ws[OFF_SB + idx] = vab;
    }
}

// ---------------- K2: split-bf16 MFMA tok GEMM, fg+bg fused, split-K-8, pipelined ----------------
// grid (63 il, 8 kc, 2 b), 256 threads. LDS 36 KB -> 4 blocks/CU.
__global__ __launch_bounds__(256)
void k2_tok(const float* __restrict__ x, const float* __restrict__ mask,
            const float* __restrict__ wsc, float* __restrict__ ws) {
    int il = blockIdx.x, kc = blockIdx.y, b = blockIdx.z;
    int tid = threadIdx.x;
    int jl = tid & 63;
    int q = tid >> 6;
    __shared__ uint16_t IN[4 * 64 * 72];   // [t*2+hl][l][72]
    const uint16_t* w2 = (const uint16_t*)(wsc + OFF_WT);

    bool lv = jl < 63;
    int lg = il * 63 + jl;

    uint32_t mbits[2] = {0u, 0u};
    if (lv) {
#pragma unroll
        for (int oi = 0; oi < 2; ++oi) {
            int o = q + oi * 4;
            const float* mp = mask + (size_t)b * 65536 + (il * 4 + o) * 256 + jl * 4;
            float4 m0 = *(const float4*)mp;
            float4 m1 = *(const float4*)(mp + 4);
            uint32_t bits = 0;
            bits |= (m0.x != 0.f) ? 1u : 0u;  bits |= (m0.y != 0.f) ? 2u : 0u;
            bits |= (m0.z != 0.f) ? 4u : 0u;  bits |= (m0.w != 0.f) ? 8u : 0u;
            bits |= (m1.x != 0.f) ? 16u : 0u; bits |= (m1.y != 0.f) ? 32u : 0u;
            bits |= (m1.z != 0.f) ? 64u : 0u; bits |= (m1.w != 0.f) ? 128u : 0u;
            mbits[oi] = bits;
        }
    }

    f32x4 acc[2][4];
#pragma unroll
    for (int t = 0; t < 2; ++t)
#pragma unroll
        for (int dq = 0; dq < 4; ++dq) acc[t][dq] = (f32x4)(0.f);

    int lane = tid & 63;
    int quad = lane >> 4;
    int lw = q * 16 + (lane & 15);

    int c0 = kc * 8;

    // pipeline registers: stats + x for current c
    float muF = 0.f, vaF = 1.f, muB = 0.f, vaB = 1.f;
    float4 xa[2][2];
#define K2_LOAD(cc)                                                                  \
    do {                                                                             \
        if (lv) {                                                                    \
            int si = (b * 64 + (cc)) * LP + lg;                                      \
            muF = wsc[OFF_MF + si]; vaF = wsc[OFF_SF + si];                          \
            muB = wsc[OFF_MB + si]; vaB = wsc[OFF_SB + si];                          \
            const float* xp0 = x + (size_t)(b * 64 + (cc)) * 65536 + (il * 4 + q) * 256 + jl * 4; \
            xa[0][0] = *(const float4*)xp0;                                          \
            xa[0][1] = *(const float4*)(xp0 + 4);                                    \
            const float* xp1 = xp0 + 1024;                                           \
            xa[1][0] = *(const float4*)xp1;                                          \
            xa[1][1] = *(const float4*)(xp1 + 4);                                    \
        }                                                                            \
    } while (0)

    K2_LOAD(c0);
    for (int ci = 0; ci < 8; ++ci) {
        int c = c0 + ci;
        // ---- compute split/pack from pipelined registers (VALU, pre-barrier) ----
        float invF = 1.0f / vaF, invB = 1.0f / vaB;
        uint4 st[2][4];
#pragma unroll
        for (int oi = 0; oi < 2; ++oi) {
            float xv[8];
            xv[0] = xa[oi][0].x; xv[1] = xa[oi][0].y; xv[2] = xa[oi][0].z; xv[3] = xa[oi][0].w;
            xv[4] = xa[oi][1].x; xv[5] = xa[oi][1].y; xv[6] = xa[oi][1].z; xv[7] = xa[oi][1].w;
            uint16_t fh[8], fl[8], bh[8], bl[8];
#pragma unroll
            for (int j = 0; j < 8; ++j) {
                float v = lv ? xv[j] : 0.f;
                bool mf = (mbits[oi] >> j) & 1;
                float fval = mf ? (v - muF) * invF : muF;
                float bval = mf ? muB : (v - muB) * invB;
                if (!lv) { fval = 0.f; bval = 0.f; }
                split_bf16(fval, fh[j], fl[j]);
                split_bf16(bval, bh[j], bl[j]);
            }
            st[oi][0] = pack8(fh); st[oi][1] = pack8(fl);
            st[oi][2] = pack8(bh); st[oi][3] = pack8(bl);
        }
        __syncthreads();   // previous MFMA reads done before overwrite
#pragma unroll
        for (int oi = 0; oi < 2; ++oi) {
            int o = q + oi * 4;
            uint16_t* p = &IN[jl * 72 + o * 8];
            *(uint4*)(p)         = st[oi][0];
            *(uint4*)(p + 4608)  = st[oi][1];
            *(uint4*)(p + 9216)  = st[oi][2];
            *(uint4*)(p + 13824) = st[oi][3];
        }
        // ---- prefetch next c while MFMA section runs ----
        if (ci < 7) K2_LOAD(c + 1);
        __syncthreads();
        // ---- MFMA: D[d][l] += W[k][d] * IN[k][l], 3-term split ----
#pragma unroll
        for (int kci = 0; kci < 2; ++kci) {
            bf16x8 Bf[2][2];
#pragma unroll
            for (int t = 0; t < 2; ++t)
#pragma unroll
                for (int hl = 0; hl < 2; ++hl)
                    Bf[t][hl] = *(bf16x8*)&IN[(t * 2 + hl) * 4608 + lw * 72 + kci * 32 + quad * 8];
#pragma unroll
            for (int dq = 0; dq < 4; ++dq) {
#pragma unroll
                for (int t = 0; t < 2; ++t) {
                    const uint16_t* ab =
                        w2 + ((size_t)(((t * 64 + c) * 2 + kci) * 4 + dq) * 2) * 512 + lane * 8;
                    bf16x8 Ah = *(const bf16x8*)ab;
                    bf16x8 Al = *(const bf16x8*)(ab + 512);
                    acc[t][dq] = __builtin_amdgcn_mfma_f32_16x16x32_bf16(Ah, Bf[t][0], acc[t][dq], 0, 0, 0);
                    acc[t][dq] = __builtin_amdgcn_mfma_f32_16x16x32_bf16(Ah, Bf[t][1], acc[t][dq], 0, 0, 0);
                    acc[t][dq] = __builtin_amdgcn_mfma_f32_16x16x32_bf16(Al, Bf[t][0], acc[t][dq], 0, 0, 0);
                }
            }
        }
    }
#undef K2_LOAD
    // epilogue: C/D row(d)=quad*4+reg (+dq*16), col(l)=lane&15 (+q*16); tok is [l][c]
    int nl = q * 16 + (lane & 15);
    if (nl < 63) {
        int lg2 = il * 63 + nl;
#pragma unroll
        for (int t = 0; t < 2; ++t) {
            float* tok = ws + (t ? OFF_TOKB : OFF_TOKF) + (size_t)b * LP * 64;
#pragma unroll
            for (int dq = 0; dq < 4; ++dq)
#pragma unroll
                for (int r = 0; r < 4; ++r)
                    atomicAdd(&tok[(size_t)lg2 * 64 + dq * 16 + quad * 4 + r], acc[t][dq][r]);
        }
    }
}

// ---------------- K3: MFMA flash attention over patch-rows ----------------
// grid (63 il, MH imc, 2 b), 256 threads.
__global__ __launch_bounds__(256)
void k3_attn(const float* __restrict__ wsc, const float* __restrict__ rpb,
             float* __restrict__ ws) {
    int il = blockIdx.x, imc = blockIdx.y, b = blockIdx.z;
    int tid = threadIdx.x;
    int w = tid >> 6, lane = tid & 63;
    int c16 = lane & 15, quad = lane >> 4;

    __shared__ uint16_t TFh[64 * 72], TFl[64 * 72];   // tok_f [l][c] hi/lo
    __shared__ uint16_t TBh[64 * 72];                 // tok_b hi [m][c]; aliased as P [l][m]
    __shared__ uint16_t TBl[64 * 72];                 // tok_b lo
    __shared__ uint16_t SB[64 * 72];                  // sb [c][m] bf16
    __shared__ float bias_r[128];

    const float* TOKF = wsc + OFF_TOKF + (size_t)b * LP * 64;
    const float* TOKB = wsc + OFF_TOKB + (size_t)b * LP * 64;
    const float* SBg  = wsc + OFF_SB + (size_t)b * 64 * LP;   // [c][LP]

    {
        int jl = tid >> 2, cc = (tid & 3) * 16;
        bool v = jl < 63;
        const float* src = TOKF + (size_t)(il * 63 + jl) * 64 + cc;
        uint16_t hh[16], lo[16];
#pragma unroll
        for (int u = 0; u < 16; u += 4) {
            float4 f = v ? *(const float4*)(src + u) : make_float4(0.f, 0.f, 0.f, 0.f);
            split_bf16(f.x, hh[u], lo[u]);     split_bf16(f.y, hh[u + 1], lo[u + 1]);
            split_bf16(f.z, hh[u + 2], lo[u + 2]); split_bf16(f.w, hh[u + 3], lo[u + 3]);
        }
        *(uint4*)&TFh[jl * 72 + cc] = pack8(hh); *(uint4*)&TFh[jl * 72 + cc + 8] = pack8(hh + 8);
        *(uint4*)&TFl[jl * 72 + cc] = pack8(lo); *(uint4*)&TFl[jl * 72 + cc + 8] = pack8(lo + 8);
    }

    float mrun[4] = {-1e30f, -1e30f, -1e30f, -1e30f};
    float drun[4] = {0.f, 0.f, 0.f, 0.f};
    f32x4 acc2[4];
#pragma unroll
    for (int ct = 0; ct < 4; ++ct) acc2[ct] = (f32x4)(0.f);

    int im0 = imc * IMR;
    int im1 = min(63, im0 + IMR);
    for (int im = im0; im < im1; ++im) {
        __syncthreads();
        {
            int jm = tid >> 2, cc = (tid & 3) * 16;
            bool v = jm < 63;
            const float* src = TOKB + (size_t)(im * 63 + jm) * 64 + cc;
            uint16_t hh[16], lo[16];
#pragma unroll
            for (int u = 0; u < 16; u += 4) {
                float4 f = v ? *(const float4*)(src + u) : make_float4(0.f, 0.f, 0.f, 0.f);
                split_bf16(f.x, hh[u], lo[u]);     split_bf16(f.y, hh[u + 1], lo[u + 1]);
                split_bf16(f.z, hh[u + 2], lo[u + 2]); split_bf16(f.w, hh[u + 3], lo[u + 3]);
            }
            *(uint4*)&TBh[jm * 72 + cc] = pack8(hh); *(uint4*)&TBh[jm * 72 + cc + 8] = pack8(hh + 8);
            *(uint4*)&TBl[jm * 72 + cc] = pack8(lo); *(uint4*)&TBl[jm * 72 + cc + 8] = pack8(lo + 8);
        }
        {
            int c = tid >> 2, mm = (tid & 3) * 16;
            const float* src = SBg + (size_t)c * LP + im * 63 + mm;
            uint16_t sv[16];
#pragma unroll
            for (int u = 0; u < 16; ++u)
                sv[u] = (mm + u < 63) ? bf16_rne(src[u]) : (uint16_t)0;
            *(uint4*)&SB[c * 72 + mm] = pack8(sv); *(uint4*)&SB[c * 72 + mm + 8] = pack8(sv + 8);
        }
        if (tid < 125) bias_r[tid] = rpb[(il - im + 62) * 125 + tid];
        else if (tid < 128) bias_r[tid] = 0.f;
        __syncthreads();

        f32x4 Z[4];
#pragma unroll
        for (int jt = 0; jt < 4; ++jt) Z[jt] = (f32x4)(0.f);
#pragma unroll
        for (int kk = 0; kk < 2; ++kk) {
            bf16x8 Ah = *(bf16x8*)&TFh[(w * 16 + c16) * 72 + kk * 32 + quad * 8];
            bf16x8 Al = *(bf16x8*)&TFl[(w * 16 + c16) * 72 + kk * 32 + quad * 8];
#pragma unroll
            for (int jt = 0; jt < 4; ++jt) {
                bf16x8 Bh = *(bf16x8*)&TBh[(jt * 16 + c16) * 72 + kk * 32 + quad * 8];
                bf16x8 Bl = *(bf16x8*)&TBl[(jt * 16 + c16) * 72 + kk * 32 + quad * 8];
                Z[jt] = __builtin_amdgcn_mfma_f32_16x16x32_bf16(Ah, Bh, Z[jt], 0, 0, 0);
                Z[jt] = __builtin_amdgcn_mfma_f32_16x16x32_bf16(Ah, Bl, Z[jt], 0, 0, 0);
                Z[jt] = __builtin_amdgcn_mfma_f32_16x16x32_bf16(Al, Bh, Z[jt], 0, 0, 0);
            }
        }
        float zv[4][4];
#pragma unroll
        for (int jt = 0; jt < 4; ++jt) {
            int jm = jt * 16 + c16;
#pragma unroll
            for (int r = 0; r < 4; ++r) {
                int i = w * 16 + quad * 4 + r;
                zv[jt][r] = (jm == 63) ? -1e30f : (Z[jt][r] + bias_r[i - jm + 62]);
            }
        }
        float alphav[4];
        uint16_t pb[4][4];
#pragma unroll
        for (int r = 0; r < 4; ++r) {
            float v = fmaxf(fmaxf(zv[0][r], zv[1][r]), fmaxf(zv[2][r], zv[3][r]));
            v = fmaxf(v, __shfl_xor(v, 1));
            v = fmaxf(v, __shfl_xor(v, 2));
            v = fmaxf(v, __shfl_xor(v, 4));
            v = fmaxf(v, __shfl_xor(v, 8));
            float mnew = fmaxf(mrun[r], v);
            alphav[r] = exp2f((mrun[r] - mnew) * LOG2E);
            float s = 0.f;
#pragma unroll
            for (int jt = 0; jt < 4; ++jt) {
                float p = exp2f((zv[jt][r] - mnew) * LOG2E);
                uint16_t h = bf16_rne(p);
                pb[jt][r] = h;
                s += __uint_as_float((uint32_t)h << 16);
            }
            s += __shfl_xor(s, 1); s += __shfl_xor(s, 2);
            s += __shfl_xor(s, 4); s += __shfl_xor(s, 8);
            drun[r] = drun[r] * alphav[r] + s;
            mrun[r] = mnew;
        }
#pragma unroll
        for (int ct = 0; ct < 4; ++ct)
#pragma unroll
            for (int r = 0; r < 4; ++r) acc2[ct][r] *= alphav[r];

        __syncthreads();
#pragma unroll
        for (int jt = 0; jt < 4; ++jt)
#pragma unroll
            for (int r = 0; r < 4; ++r)
                TBh[(w * 16 + quad * 4 + r) * 72 + jt * 16 + c16] = pb[jt][r];
        __syncthreads();

#pragma unroll
        for (int kk = 0; kk < 2; ++kk) {
            bf16x8 Pf = *(bf16x8*)&TBh[(w * 16 + c16) * 72 + kk * 32 + quad * 8];
#pragma unroll
            for (int ct = 0; ct < 4; ++ct) {
                bf16x8 Sf = *(bf16x8*)&SB[(ct * 16 + c16) * 72 + kk * 32 + quad * 8];
                acc2[ct] = __builtin_amdgcn_mfma_f32_16x16x32_bf16(Pf, Sf, acc2[ct], 0, 0, 0);
            }
        }
    }
    float* PA = ws + OFF_PACC + ((imc * 2 + b) * (size_t)LP) * 64;
#pragma unroll
    for (int r = 0; r < 4; ++r) {
        int i = w * 16 + quad * 4 + r;
        if (i < 63) {
            int rl = il * 63 + i;
#pragma unroll
            for (int ct = 0; ct < 4; ++ct)
                PA[(size_t)rl * 64 + ct * 16 + c16] = acc2[ct][r];
            if (c16 == 0) {
                ws[OFF_PM + (imc * 2 + b) * LP + rl] = mrun[r];
                ws[OFF_PD + (imc * 2 + b) * LP + rl] = drun[r];
            }
        }
    }
}

// ---------------- K3b: merge the MH m-slices; result lands in PACC slice 0 ----------------
__global__ void k3b_merge(float* __restrict__ ws) {
    int b = blockIdx.y;
    int l = blockIdx.x * 4 + (threadIdx.x >> 6);
    int c = threadIdx.x & 63;
    if (l >= L_) return;
    float M = -1e30f;
#pragma unroll
    for (int p = 0; p < MH; ++p)
        M = fmaxf(M, ws[OFF_PM + (p * 2 + b) * LP + l]);
    float denom = 0.f, num = 0.f;
#pragma unroll
    for (int p = 0; p < MH; ++p) {
        float w = exp2f((ws[OFF_PM + (p * 2 + b) * LP + l] - M) * LOG2E);
        denom += ws[OFF_PD + (p * 2 + b) * LP + l] * w;
        num += ws[OFF_PACC + ((p * 2 + b) * (size_t)LP + l) * 64 + c] * w;
    }
    ws[OFF_PACC + (b * (size_t)LP + l) * 64 + c] = num / denom;
}

// ---------------- K4: fold + affines + compose output ----------------
__global__ void k4_fold(const float* __restrict__ x, const float* __restrict__ mask,
                        const float* __restrict__ fg_g, const float* __restrict__ fg_b,
                        const float* __restrict__ bg_g, const float* __restrict__ bg_b,
                        const float* __restrict__ wsc, float* __restrict__ out) {
    int gid = blockIdx.x * 256 + threadIdx.x;
    int col = gid & 255, r = (gid >> 8) & 255, c = (gid >> 16) & 63, b = gid >> 22;
    float xv = x[gid];
    float m = mask[b * 65536 + r * 256 + col];
    int imin = (r >= 4) ? ((r - 4) >> 2) : 0;
    int imax = min(62, r >> 2);
    int jmin = (col >= 4) ? ((col - 4) >> 2) : 0;
    int jmax = min(62, col >> 2);
    const float* MF = wsc + OFF_MF + (b * 64 + c) * LP;
    const float* SF = wsc + OFF_SF + (b * 64 + c) * LP;
    const float* NS = wsc + OFF_PACC + b * (size_t)LP * 64;  // merged NSTD (slice 0)
    float folded = 0.f;
    int cnt = (imax - imin + 1) * (jmax - jmin + 1);
    for (int i = imin; i <= imax; ++i)
        for (int j = jmin; j <= jmax; ++j) {
            int l = i * 63 + j;
            float mf = MF[l], sf = SF[l];
            float inf_ = (m != 0.f) ? (xv - mf) / sf : mf;
            folded += NS[l * 64 + c] * (inf_ + 1.f);
        }
    float invm = 1.f - m;
    float ub = (xv * invm * (1.f + bg_g[c]) + bg_b[c]) * invm;
    float nf = (folded / (float)cnt * (1.f + fg_g[c]) + fg_b[c]) * m;
    out[gid] = nf + ub;
}

extern "C" void kernel_launch(void* const* d_in, const int* in_sizes, int n_in,
                              void* d_out, int out_size, void* d_ws, size_t ws_size,
                              hipStream_t stream) {
    const float* x    = (const float*)d_in[0];
    const float* mask = (const float*)d_in[1];
    const float* fg_g = (const float*)d_in[2];
    const float* fg_b = (const float*)d_in[3];
    const float* bg_g = (const float*)d_in[4];
    const float* bg_b = (const float*)d_in[5];
    const float* wf   = (const float*)d_in[6];
    const float* wb   = (const float*)d_in[7];
    const float* rpb  = (const float*)d_in[8];
    float* ws = (float*)d_ws;
    float* out = (float*)d_out;

    k0_w2<<<dim3(64, 2), 256, 0, stream>>>(wf, wb, ws);
    k1_stats<<<dim3(63, 64, 2), 256, 0, stream>>>(x, mask, ws);
    hipMemsetAsync(ws + OFF_TOKF, 0, (size_t)1016832 * sizeof(float), stream);
    k2_tok<<<dim3(63, 8, 2), 256, 0, stream>>>(x, mask, ws, ws);
    k3_attn<<<dim3(63, MH, 2), 256, 0, stream>>>(ws, rpb, ws);
    k3b_merge<<<dim3(993, 2), 256, 0, stream>>>(ws);
    k4_fold<<<dim3(32768), 256, 0, stream>>>(x, mask, fg_g, fg_b, bg_g, bg_b, ws, out);
}

// Round 6
// 316.290 us; speedup vs baseline: 1.2273x; 1.2273x over previous
//
#include <hip/hip_runtime.h>
#include <stdint.h>

// Problem constants
#define L_   3969         // patches
#define LP   3972         // padded L (mult of 4, for float4 loads)
#define EPS_ 1e-5f
#define LOG2E 1.4426950408889634f
#define MH   6            // split over im (patch-row chunks) in K3
#define IMR  11           // im rows per chunk (6*11 >= 63)

// workspace layout (float offsets). Total 6,720,608 floats = 26.9 MB
#define OFF_MF   0          // [2][64][LP] fg mean
#define OFF_SF   508416     // fg var
#define OFF_MB   1016832    // bg mean
#define OFF_SB   1525248    // bg var
#define OFF_TOKF 2033664    // [2 b][LP][64 c]; PART slice kc=0 (t=0 half)
#define OFF_TOKB 2542080    //                 PART slice kc=0 (t=1 half)
#define OFF_PACC 3050496    // [MH][2 b][LP][64]; also PART slices kc=1..3 (dead until k3)
#define OFF_PM   6100992    // [MH][2][LP]
#define OFF_PD   6148656
#define OFF_WT   6196320    // W2: bf16 frag-ordered weights (1M bf16)
#define PART_SLICE 1016832  // floats per kc slice: [2 t][2 b][LP][64]

typedef __attribute__((ext_vector_type(8))) short bf16x8;   // 8 bf16 (4 VGPRs)
typedef __attribute__((ext_vector_type(4))) float f32x4;    // MFMA accumulator

__device__ __forceinline__ uint16_t bf16_rne(float f) {
    uint32_t u = __float_as_uint(f);
    return (uint16_t)((u + 0x7FFFu + ((u >> 16) & 1u)) >> 16);
}
// hi = truncated top-16 bits (exact), lo = RNE(residual): hi+lo ~ 2^-17 relative
__device__ __forceinline__ void split_bf16(float v, uint16_t& h, uint16_t& l) {
    uint32_t u = __float_as_uint(v);
    uint32_t hu = u & 0xFFFF0000u;
    h = (uint16_t)(hu >> 16);
    l = bf16_rne(v - __uint_as_float(hu));
}
__device__ __forceinline__ uint4 pack8(const uint16_t* s) {
    uint4 r;
    r.x = (uint32_t)s[0] | ((uint32_t)s[1] << 16);
    r.y = (uint32_t)s[2] | ((uint32_t)s[3] << 16);
    r.z = (uint32_t)s[4] | ((uint32_t)s[5] << 16);
    r.w = (uint32_t)s[6] | ((uint32_t)s[7] << 16);
    return r;
}

// ---------------- K0: weights -> split-bf16 MFMA A-fragment layout ----------------
__global__ void k0_w2(const float* __restrict__ wf, const float* __restrict__ wb,
                      float* __restrict__ ws) {
    int c = blockIdx.x, t = blockIdx.y;
    const float* w = t ? wb : wf;
    uint16_t* w2 = (uint16_t*)(ws + OFF_WT);
    int tid = threadIdx.x;
    int lane = tid & 63, dq = tid >> 6;
    int d = dq * 16 + (lane & 15), quad = lane >> 4;
    for (int kci = 0; kci < 2; ++kci) {
        int k = kci * 32 + quad * 8;
        const float* src = w + (size_t)(d * 64 + c) * 64 + k;
        uint16_t hb[8], lb[8];
#pragma unroll
        for (int j = 0; j < 8; ++j) split_bf16(src[j], hb[j], lb[j]);
        size_t base = ((size_t)(((t * 64 + c) * 2 + kci) * 4 + dq) * 2) * 512 + lane * 8;
        *(uint4*)(w2 + base) = pack8(hb);
        *(uint4*)(w2 + base + 512) = pack8(lb);
    }
}

// ---------------- K1: per-patch fg/bg stats ----------------
__global__ void k1_stats(const float* __restrict__ x, const float* __restrict__ mask,
                         float* __restrict__ ws) {
    int i = blockIdx.x, c = blockIdx.y, b = blockIdx.z;
    __shared__ float xs[8 * 256];
    __shared__ float ms[8 * 256];
    __shared__ float pS[5][256];
    int t = threadIdx.x;
    const float* xr = x + (((b * 64 + c) * 256) + i * 4) * 256;
    const float* mr = mask + (b * 256 + i * 4) * 256;
#pragma unroll
    for (int r = 0; r < 8; ++r) {
        xs[r * 256 + t] = xr[r * 256 + t];
        ms[r * 256 + t] = mr[r * 256 + t];
    }
    __syncthreads();
    int q = t >> 6, j = t & 63;
    float Sa = 0, Qa = 0, Sf = 0, Qf = 0, Nf = 0;
    if (j < 63) {
#pragma unroll
        for (int rr = 0; rr < 2; ++rr) {
            int base = (q * 2 + rr) * 256 + j * 4;
#pragma unroll
            for (int cc = 0; cc < 8; ++cc) {
                float v = xs[base + cc], m = ms[base + cc];
                Sa += v; Qa += v * v; Sf += v * m; Qf += v * v * m; Nf += m;
            }
        }
    }
    pS[0][t] = Sa; pS[1][t] = Qa; pS[2][t] = Sf; pS[3][t] = Qf; pS[4][t] = Nf;
    __syncthreads();
    if (q == 0 && j < 63) {
        Sa = pS[0][j] + pS[0][j + 64] + pS[0][j + 128] + pS[0][j + 192];
        Qa = pS[1][j] + pS[1][j + 64] + pS[1][j + 128] + pS[1][j + 192];
        Sf = pS[2][j] + pS[2][j + 64] + pS[2][j + 128] + pS[2][j + 192];
        Qf = pS[3][j] + pS[3][j + 64] + pS[3][j + 128] + pS[3][j + 192];
        Nf = pS[4][j] + pS[4][j + 64] + pS[4][j + 128] + pS[4][j + 192];
        float nb = 64.0f - Nf;
        float muf = Sf / (Nf + EPS_);
        float vaf = (Qf - 2.f * muf * Sf + Nf * muf * muf) / (Nf + EPS_);
        float Sb = Sa - Sf, Qb = Qa - Qf;
        float mub = Sb / (nb + EPS_);
        float vab = (Qb - 2.f * mub * Sb + nb * mub * mub) / (nb + EPS_);
        int idx = (b * 64 + c) * LP + i * 63 + j;
        ws[OFF_MF + idx] = muf; ws[OFF_SF + idx] = vaf;
        ws[OFF_MB + idx] = mub; ws[OFF_SB + idx] = vab;
    }
}

// ---------------- K2: split-bf16 MFMA tok GEMM, no atomics, 2-channel stages ----------------
// grid (63 il, 4 kc, 2 b), 256 threads. LDS 72 KB -> 2 blocks/CU.
__global__ __launch_bounds__(256)
void k2_tok(const float* __restrict__ x, const float* __restrict__ mask,
            const float* __restrict__ wsc, float* __restrict__ ws) {
    int il = blockIdx.x, kc = blockIdx.y, b = blockIdx.z;
    int tid = threadIdx.x;
    int jl = tid & 63;
    int q = tid >> 6;
    __shared__ uint16_t IN[2][4 * 64 * 72];   // [cpair][t*2+hl][l][72]
    const uint16_t* w2 = (const uint16_t*)(wsc + OFF_WT);

    bool lv = jl < 63;
    int lg = il * 63 + jl;

    uint32_t mbits[2] = {0u, 0u};
    if (lv) {
#pragma unroll
        for (int oi = 0; oi < 2; ++oi) {
            int o = q + oi * 4;
            const float* mp = mask + (size_t)b * 65536 + (il * 4 + o) * 256 + jl * 4;
            float4 m0 = *(const float4*)mp;
            float4 m1 = *(const float4*)(mp + 4);
            uint32_t bits = 0;
            bits |= (m0.x != 0.f) ? 1u : 0u;  bits |= (m0.y != 0.f) ? 2u : 0u;
            bits |= (m0.z != 0.f) ? 4u : 0u;  bits |= (m0.w != 0.f) ? 8u : 0u;
            bits |= (m1.x != 0.f) ? 16u : 0u; bits |= (m1.y != 0.f) ? 32u : 0u;
            bits |= (m1.z != 0.f) ? 64u : 0u; bits |= (m1.w != 0.f) ? 128u : 0u;
            mbits[oi] = bits;
        }
    }

    f32x4 acc[2][4];
#pragma unroll
    for (int t = 0; t < 2; ++t)
#pragma unroll
        for (int dq = 0; dq < 4; ++dq) acc[t][dq] = (f32x4)(0.f);

    int lane = tid & 63;
    int quad = lane >> 4;
    int lw = q * 16 + (lane & 15);

    int c0 = kc * 16;

    // pipeline registers for a PAIR of channels
    float muF[2], vaF[2], muB[2], vaB[2];
    float4 xa[2][2][2];   // [p][oi][half]
#define K2_LOADPAIR(cb)                                                              \
    do {                                                                             \
        if (lv) {                                                                    \
            _Pragma("unroll")                                                        \
            for (int p = 0; p < 2; ++p) {                                            \
                int cc = (cb) + p;                                                   \
                int si = (b * 64 + cc) * LP + lg;                                    \
                muF[p] = wsc[OFF_MF + si]; vaF[p] = wsc[OFF_SF + si];                \
                muB[p] = wsc[OFF_MB + si]; vaB[p] = wsc[OFF_SB + si];                \
                const float* xp0 = x + (size_t)(b * 64 + cc) * 65536 + (il * 4 + q) * 256 + jl * 4; \
                xa[p][0][0] = *(const float4*)xp0;                                   \
                xa[p][0][1] = *(const float4*)(xp0 + 4);                             \
                xa[p][1][0] = *(const float4*)(xp0 + 1024);                          \
                xa[p][1][1] = *(const float4*)(xp0 + 1028);                          \
            }                                                                        \
        }                                                                            \
    } while (0)

    K2_LOADPAIR(c0);
    for (int pi = 0; pi < 8; ++pi) {
        int cbase = c0 + pi * 2;
        // ---- pack both channels (VALU, pre-barrier; waits on prefetched loads) ----
        uint4 st[2][2][4];
#pragma unroll
        for (int p = 0; p < 2; ++p) {
            float invF = 1.0f / vaF[p], invB = 1.0f / vaB[p];
#pragma unroll
            for (int oi = 0; oi < 2; ++oi) {
                float xv[8];
                xv[0] = xa[p][oi][0].x; xv[1] = xa[p][oi][0].y;
                xv[2] = xa[p][oi][0].z; xv[3] = xa[p][oi][0].w;
                xv[4] = xa[p][oi][1].x; xv[5] = xa[p][oi][1].y;
                xv[6] = xa[p][oi][1].z; xv[7] = xa[p][oi][1].w;
                uint16_t fh[8], fl[8], bh[8], bl[8];
#pragma unroll
                for (int j = 0; j < 8; ++j) {
                    float v = lv ? xv[j] : 0.f;
                    bool mf = (mbits[oi] >> j) & 1;
                    float fval = mf ? (v - muF[p]) * invF : muF[p];
                    float bval = mf ? muB[p] : (v - muB[p]) * invB;
                    if (!lv) { fval = 0.f; bval = 0.f; }
                    split_bf16(fval, fh[j], fl[j]);
                    split_bf16(bval, bh[j], bl[j]);
                }
                st[p][oi][0] = pack8(fh); st[p][oi][1] = pack8(fl);
                st[p][oi][2] = pack8(bh); st[p][oi][3] = pack8(bl);
            }
        }
        __syncthreads();   // previous MFMA reads done before overwrite
#pragma unroll
        for (int p = 0; p < 2; ++p)
#pragma unroll
            for (int oi = 0; oi < 2; ++oi) {
                int o = q + oi * 4;
                uint16_t* dst = &IN[p][jl * 72 + o * 8];
                *(uint4*)(dst)         = st[p][oi][0];
                *(uint4*)(dst + 4608)  = st[p][oi][1];
                *(uint4*)(dst + 9216)  = st[p][oi][2];
                *(uint4*)(dst + 13824) = st[p][oi][3];
            }
        __syncthreads();
        // ---- prefetch next pair AFTER the barrier: drains only at next sync1 ----
        if (pi < 7) K2_LOADPAIR(cbase + 2);
        // ---- MFMA phase: 96 MFMAs/wave over the 2 staged channels ----
#pragma unroll
        for (int p = 0; p < 2; ++p) {
            int c = cbase + p;
#pragma unroll
            for (int kci = 0; kci < 2; ++kci) {
                bf16x8 Bf[2][2];
#pragma unroll
                for (int t = 0; t < 2; ++t)
#pragma unroll
                    for (int hl = 0; hl < 2; ++hl)
                        Bf[t][hl] = *(bf16x8*)&IN[p][(t * 2 + hl) * 4608 + lw * 72 + kci * 32 + quad * 8];
#pragma unroll
                for (int dq = 0; dq < 4; ++dq) {
#pragma unroll
                    for (int t = 0; t < 2; ++t) {
                        const uint16_t* ab =
                            w2 + ((size_t)(((t * 64 + c) * 2 + kci) * 4 + dq) * 2) * 512 + lane * 8;
                        bf16x8 Ah = *(const bf16x8*)ab;
                        bf16x8 Al = *(const bf16x8*)(ab + 512);
                        acc[t][dq] = __builtin_amdgcn_mfma_f32_16x16x32_bf16(Ah, Bf[t][0], acc[t][dq], 0, 0, 0);
                        acc[t][dq] = __builtin_amdgcn_mfma_f32_16x16x32_bf16(Ah, Bf[t][1], acc[t][dq], 0, 0, 0);
                        acc[t][dq] = __builtin_amdgcn_mfma_f32_16x16x32_bf16(Al, Bf[t][0], acc[t][dq], 0, 0, 0);
                    }
                }
            }
        }
    }
#undef K2_LOADPAIR
    // ---- epilogue: LDS transpose -> coalesced float4 stores to PART (no atomics) ----
    // C/D: row(d)=dq*16+quad*4+r, col(l)=q*16+(lane&15)
    float* ST = (float*)&IN[0][0];   // 64 l x 68 d floats = 17.4 KB, fits
    int nl = q * 16 + (lane & 15);
#pragma unroll
    for (int t = 0; t < 2; ++t) {
        __syncthreads();   // MFMA reads (t=0) / prior writeout (t=1) done
#pragma unroll
        for (int dq = 0; dq < 4; ++dq)
#pragma unroll
            for (int r = 0; r < 4; ++r)
                ST[nl * 68 + dq * 16 + quad * 4 + r] = acc[t][dq][r];
        __syncthreads();
        float* dst = ws + OFF_TOKF + (size_t)kc * PART_SLICE + ((t * 2 + b) * (size_t)LP) * 64;
        int d4 = (tid & 15) * 4;
#pragma unroll
        for (int pass = 0; pass < 4; ++pass) {
            int l = pass * 16 + (tid >> 4);
            if (l < 63)
                *(float4*)&dst[(size_t)(il * 63 + l) * 64 + d4] = *(float4*)&ST[l * 68 + d4];
        }
    }
}

// ---------------- K2r: reduce 4 kc partial slices into slice 0 (= TOKF/TOKB) ----------------
__global__ void k2r_reduce(float* __restrict__ ws) {
    size_t i = ((size_t)blockIdx.x * 256 + threadIdx.x) * 4;
    float4 a0 = *(float4*)&ws[OFF_TOKF + i];
    float4 a1 = *(float4*)&ws[OFF_TOKF + PART_SLICE + i];
    float4 a2 = *(float4*)&ws[OFF_TOKF + 2 * PART_SLICE + i];
    float4 a3 = *(float4*)&ws[OFF_TOKF + 3 * PART_SLICE + i];
    a0.x += a1.x + a2.x + a3.x; a0.y += a1.y + a2.y + a3.y;
    a0.z += a1.z + a2.z + a3.z; a0.w += a1.w + a2.w + a3.w;
    *(float4*)&ws[OFF_TOKF + i] = a0;
}

// ---------------- K3: MFMA flash attention over patch-rows ----------------
// grid (63 il, MH imc, 2 b), 256 threads.
__global__ __launch_bounds__(256)
void k3_attn(const float* __restrict__ wsc, const float* __restrict__ rpb,
             float* __restrict__ ws) {
    int il = blockIdx.x, imc = blockIdx.y, b = blockIdx.z;
    int tid = threadIdx.x;
    int w = tid >> 6, lane = tid & 63;
    int c16 = lane & 15, quad = lane >> 4;

    __shared__ uint16_t TFh[64 * 72], TFl[64 * 72];   // tok_f [l][c] hi/lo
    __shared__ uint16_t TBh[64 * 72];                 // tok_b hi [m][c]; aliased as P [l][m]
    __shared__ uint16_t TBl[64 * 72];                 // tok_b lo
    __shared__ uint16_t SB[64 * 72];                  // sb [c][m] bf16
    __shared__ float bias_r[128];

    const float* TOKF = wsc + OFF_TOKF + (size_t)b * LP * 64;
    const float* TOKB = wsc + OFF_TOKB + (size_t)b * LP * 64;
    const float* SBg  = wsc + OFF_SB + (size_t)b * 64 * LP;   // [c][LP]

    {
        int jl = tid >> 2, cc = (tid & 3) * 16;
        bool v = jl < 63;
        const float* src = TOKF + (size_t)(il * 63 + jl) * 64 + cc;
        uint16_t hh[16], lo[16];
#pragma unroll
        for (int u = 0; u < 16; u += 4) {
            float4 f = v ? *(const float4*)(src + u) : make_float4(0.f, 0.f, 0.f, 0.f);
            split_bf16(f.x, hh[u], lo[u]);     split_bf16(f.y, hh[u + 1], lo[u + 1]);
            split_bf16(f.z, hh[u + 2], lo[u + 2]); split_bf16(f.w, hh[u + 3], lo[u + 3]);
        }
        *(uint4*)&TFh[jl * 72 + cc] = pack8(hh); *(uint4*)&TFh[jl * 72 + cc + 8] = pack8(hh + 8);
        *(uint4*)&TFl[jl * 72 + cc] = pack8(lo); *(uint4*)&TFl[jl * 72 + cc + 8] = pack8(lo + 8);
    }

    float mrun[4] = {-1e30f, -1e30f, -1e30f, -1e30f};
    float drun[4] = {0.f, 0.f, 0.f, 0.f};
    f32x4 acc2[4];
#pragma unroll
    for (int ct = 0; ct < 4; ++ct) acc2[ct] = (f32x4)(0.f);

    int im0 = imc * IMR;
    int im1 = min(63, im0 + IMR);
    for (int im = im0; im < im1; ++im) {
        __syncthreads();
        {
            int jm = tid >> 2, cc = (tid & 3) * 16;
            bool v = jm < 63;
            const float* src = TOKB + (size_t)(im * 63 + jm) * 64 + cc;
            uint16_t hh[16], lo[16];
#pragma unroll
            for (int u = 0; u < 16; u += 4) {
                float4 f = v ? *(const float4*)(src + u) : make_float4(0.f, 0.f, 0.f, 0.f);
                split_bf16(f.x, hh[u], lo[u]);     split_bf16(f.y, hh[u + 1], lo[u + 1]);
                split_bf16(f.z, hh[u + 2], lo[u + 2]); split_bf16(f.w, hh[u + 3], lo[u + 3]);
            }
            *(uint4*)&TBh[jm * 72 + cc] = pack8(hh); *(uint4*)&TBh[jm * 72 + cc + 8] = pack8(hh + 8);
            *(uint4*)&TBl[jm * 72 + cc] = pack8(lo); *(uint4*)&TBl[jm * 72 + cc + 8] = pack8(lo + 8);
        }
        {
            int c = tid >> 2, mm = (tid & 3) * 16;
            const float* src = SBg + (size_t)c * LP + im * 63 + mm;
            uint16_t sv[16];
#pragma unroll
            for (int u = 0; u < 16; ++u)
                sv[u] = (mm + u < 63) ? bf16_rne(src[u]) : (uint16_t)0;
            *(uint4*)&SB[c * 72 + mm] = pack8(sv); *(uint4*)&SB[c * 72 + mm + 8] = pack8(sv + 8);
        }
        if (tid < 125) bias_r[tid] = rpb[(il - im + 62) * 125 + tid];
        else if (tid < 128) bias_r[tid] = 0.f;
        __syncthreads();

        f32x4 Z[4];
#pragma unroll
        for (int jt = 0; jt < 4; ++jt) Z[jt] = (f32x4)(0.f);
#pragma unroll
        for (int kk = 0; kk < 2; ++kk) {
            bf16x8 Ah = *(bf16x8*)&TFh[(w * 16 + c16) * 72 + kk * 32 + quad * 8];
            bf16x8 Al = *(bf16x8*)&TFl[(w * 16 + c16) * 72 + kk * 32 + quad * 8];
#pragma unroll
            for (int jt = 0; jt < 4; ++jt) {
                bf16x8 Bh = *(bf16x8*)&TBh[(jt * 16 + c16) * 72 + kk * 32 + quad * 8];
                bf16x8 Bl = *(bf16x8*)&TBl[(jt * 16 + c16) * 72 + kk * 32 + quad * 8];
                Z[jt] = __builtin_amdgcn_mfma_f32_16x16x32_bf16(Ah, Bh, Z[jt], 0, 0, 0);
                Z[jt] = __builtin_amdgcn_mfma_f32_16x16x32_bf16(Ah, Bl, Z[jt], 0, 0, 0);
                Z[jt] = __builtin_amdgcn_mfma_f32_16x16x32_bf16(Al, Bh, Z[jt], 0, 0, 0);
            }
        }
        float zv[4][4];
#pragma unroll
        for (int jt = 0; jt < 4; ++jt) {
            int jm = jt * 16 + c16;
#pragma unroll
            for (int r = 0; r < 4; ++r) {
                int i = w * 16 + quad * 4 + r;
                zv[jt][r] = (jm == 63) ? -1e30f : (Z[jt][r] + bias_r[i - jm + 62]);
            }
        }
        float alphav[4];
        uint16_t pb[4][4];
#pragma unroll
        for (int r = 0; r < 4; ++r) {
            float v = fmaxf(fmaxf(zv[0][r], zv[1][r]), fmaxf(zv[2][r], zv[3][r]));
            v = fmaxf(v, __shfl_xor(v, 1));
            v = fmaxf(v, __shfl_xor(v, 2));
            v = fmaxf(v, __shfl_xor(v, 4));
            v = fmaxf(v, __shfl_xor(v, 8));
            float mnew = fmaxf(mrun[r], v);
            alphav[r] = exp2f((mrun[r] - mnew) * LOG2E);
            float s = 0.f;
#pragma unroll
            for (int jt = 0; jt < 4; ++jt) {
                float p = exp2f((zv[jt][r] - mnew) * LOG2E);
                uint16_t h = bf16_rne(p);
                pb[jt][r] = h;
                s += __uint_as_float((uint32_t)h << 16);
            }
            s += __shfl_xor(s, 1); s += __shfl_xor(s, 2);
            s += __shfl_xor(s, 4); s += __shfl_xor(s, 8);
            drun[r] = drun[r] * alphav[r] + s;
            mrun[r] = mnew;
        }
#pragma unroll
        for (int ct = 0; ct < 4; ++ct)
#pragma unroll
            for (int r = 0; r < 4; ++r) acc2[ct][r] *= alphav[r];

        __syncthreads();
#pragma unroll
        for (int jt = 0; jt < 4; ++jt)
#pragma unroll
            for (int r = 0; r < 4; ++r)
                TBh[(w * 16 + quad * 4 + r) * 72 + jt * 16 + c16] = pb[jt][r];
        __syncthreads();

#pragma unroll
        for (int kk = 0; kk < 2; ++kk) {
            bf16x8 Pf = *(bf16x8*)&TBh[(w * 16 + c16) * 72 + kk * 32 + quad * 8];
#pragma unroll
            for (int ct = 0; ct < 4; ++ct) {
                bf16x8 Sf = *(bf16x8*)&SB[(ct * 16 + c16) * 72 + kk * 32 + quad * 8];
                acc2[ct] = __builtin_amdgcn_mfma_f32_16x16x32_bf16(Pf, Sf, acc2[ct], 0, 0, 0);
            }
        }
    }
    float* PA = ws + OFF_PACC + ((imc * 2 + b) * (size_t)LP) * 64;
#pragma unroll
    for (int r = 0; r < 4; ++r) {
        int i = w * 16 + quad * 4 + r;
        if (i < 63) {
            int rl = il * 63 + i;
#pragma unroll
            for (int ct = 0; ct < 4; ++ct)
                PA[(size_t)rl * 64 + ct * 16 + c16] = acc2[ct][r];
            if (c16 == 0) {
                ws[OFF_PM + (imc * 2 + b) * LP + rl] = mrun[r];
                ws[OFF_PD + (imc * 2 + b) * LP + rl] = drun[r];
            }
        }
    }
}

// ---------------- K3b: merge the MH m-slices; result lands in PACC slice 0 ----------------
__global__ void k3b_merge(float* __restrict__ ws) {
    int b = blockIdx.y;
    int l = blockIdx.x * 4 + (threadIdx.x >> 6);
    int c = threadIdx.x & 63;
    if (l >= L_) return;
    float M = -1e30f;
#pragma unroll
    for (int p = 0; p < MH; ++p)
        M = fmaxf(M, ws[OFF_PM + (p * 2 + b) * LP + l]);
    float denom = 0.f, num = 0.f;
#pragma unroll
    for (int p = 0; p < MH; ++p) {
        float w = exp2f((ws[OFF_PM + (p * 2 + b) * LP + l] - M) * LOG2E);
        denom += ws[OFF_PD + (p * 2 + b) * LP + l] * w;
        num += ws[OFF_PACC + ((p * 2 + b) * (size_t)LP + l) * 64 + c] * w;
    }
    ws[OFF_PACC + (b * (size_t)LP + l) * 64 + c] = num / denom;
}

// ---------------- K4: fold + affines + compose output ----------------
__global__ void k4_fold(const float* __restrict__ x, const float* __restrict__ mask,
                        const float* __restrict__ fg_g, const float* __restrict__ fg_b,
                        const float* __restrict__ bg_g, const float* __restrict__ bg_b,
                        const float* __restrict__ wsc, float* __restrict__ out) {
    int gid = blockIdx.x * 256 + threadIdx.x;
    int col = gid & 255, r = (gid >> 8) & 255, c = (gid >> 16) & 63, b = gid >> 22;
    float xv = x[gid];
    float m = mask[b * 65536 + r * 256 + col];
    int imin = (r >= 4) ? ((r - 4) >> 2) : 0;
    int imax = min(62, r >> 2);
    int jmin = (col >= 4) ? ((col - 4) >> 2) : 0;
    int jmax = min(62, col >> 2);
    const float* MF = wsc + OFF_MF + (b * 64 + c) * LP;
    const float* SF = wsc + OFF_SF + (b * 64 + c) * LP;
    const float* NS = wsc + OFF_PACC + b * (size_t)LP * 64;  // merged NSTD (slice 0)
    float folded = 0.f;
    int cnt = (imax - imin + 1) * (jmax - jmin + 1);
    for (int i = imin; i <= imax; ++i)
        for (int j = jmin; j <= jmax; ++j) {
            int l = i * 63 + j;
            float mf = MF[l], sf = SF[l];
            float inf_ = (m != 0.f) ? (xv - mf) / sf : mf;
            folded += NS[l * 64 + c] * (inf_ + 1.f);
        }
    float invm = 1.f - m;
    float ub = (xv * invm * (1.f + bg_g[c]) + bg_b[c]) * invm;
    float nf = (folded / (float)cnt * (1.f + fg_g[c]) + fg_b[c]) * m;
    out[gid] = nf + ub;
}

extern "C" void kernel_launch(void* const* d_in, const int* in_sizes, int n_in,
                              void* d_out, int out_size, void* d_ws, size_t ws_size,
                              hipStream_t stream) {
    const float* x    = (const float*)d_in[0];
    const float* mask = (const float*)d_in[1];
    const float* fg_g = (const float*)d_in[2];
    const float* fg_b = (const float*)d_in[3];
    const float* bg_g = (const float*)d_in[4];
    const float* bg_b = (const float*)d_in[5];
    const float* wf   = (const float*)d_in[6];
    const float* wb   = (const float*)d_in[7];
    const float* rpb  = (const float*)d_in[8];
    float* ws = (float*)d_ws;
    float* out = (float*)d_out;

    k0_w2<<<dim3(64, 2), 256, 0, stream>>>(wf, wb, ws);
    k1_stats<<<dim3(63, 64, 2), 256, 0, stream>>>(x, mask, ws);
    k2_tok<<<dim3(63, 4, 2), 256, 0, stream>>>(x, mask, ws, ws);
    k2r_reduce<<<dim3(993), 256, 0, stream>>>(ws);
    k3_attn<<<dim3(63, MH, 2), 256, 0, stream>>>(ws, rpb, ws);
    k3b_merge<<<dim3(993, 2), 256, 0, stream>>>(ws);
    k4_fold<<<dim3(32768), 256, 0, stream>>>(x, mask, fg_g, fg_b, bg_g, bg_b, ws, out);
}